// Round 1
// baseline (539.408 us; speedup 1.0000x reference)
//
#include <hip/hip_runtime.h>
#include <hip/hip_bf16.h>

#define B_ 16
#define C_ 256
#define H_ 128
#define W_ 128
#define K_ 12
#define HW_ (H_*W_)

__device__ __forceinline__ float gelu_f(float v){
    return 0.5f * v * (1.0f + erff(v * 0.70710678118654752f));
}

// ---------------- Kernel 1: GAP over H,W per (b,c) plane ----------------
__global__ __launch_bounds__(256) void gap_kernel(const float* __restrict__ x,
                                                  float* __restrict__ y){
    int bc = blockIdx.x;                       // b*C + c
    const float4* p = (const float4*)(x + (size_t)bc * HW_);
    float s = 0.f;
    #pragma unroll
    for (int i = 0; i < 16; ++i){
        float4 v = p[i*256 + threadIdx.x];
        s += (v.x + v.y) + (v.z + v.w);
    }
    #pragma unroll
    for (int off = 32; off > 0; off >>= 1) s += __shfl_down(s, off, 64);
    __shared__ float red[4];
    int lane = threadIdx.x & 63, wv = threadIdx.x >> 6;
    if (lane == 0) red[wv] = s;
    __syncthreads();
    if (threadIdx.x == 0)
        y[bc] = (red[0]+red[1]+red[2]+red[3]) * (1.0f/(float)HW_);
}

// ------------- Kernel 2: ECA gate + MLP + softmax + kernel agg -------------
__global__ __launch_bounds__(256) void head_kernel(
    const float* __restrict__ y, const float* __restrict__ w1,
    const float* __restrict__ b1, const float* __restrict__ w2,
    const float* __restrict__ b2, const float* __restrict__ kw,
    const float* __restrict__ eca,
    float* __restrict__ gate_out, float* __restrict__ agg_out){

    __shared__ float y_s[B_*C_];
    __shared__ float p_s[B_*C_];
    __shared__ float hdd_s[B_*C_];
    __shared__ float alpha_s[B_*K_];

    const int t = threadIdx.x;

    #pragma unroll
    for (int i = 0; i < 16; ++i) y_s[t + i*256] = y[t + i*256];
    __syncthreads();

    const float e0 = eca[0], e1 = eca[1], e2 = eca[2];
    #pragma unroll
    for (int i = 0; i < 16; ++i){
        int idx = t + i*256;
        int c = idx & (C_-1);
        float left  = (c > 0)      ? y_s[idx-1] : 0.f;
        float right = (c < C_-1)   ? y_s[idx+1] : 0.f;
        float arg = e0*left + e1*y_s[idx] + e2*right;
        float g = 1.0f / (1.0f + expf(-arg));
        gate_out[idx] = g;
        p_s[idx] = g * y_s[idx];
    }
    __syncthreads();

    // MLP layer 1: hdd[b][j] = gelu(sum_i p[b][i]*W1[i][j] + b1[j]); j = t
    {
        float acc[16];
        float bb = b1[t];
        #pragma unroll
        for (int b = 0; b < 16; ++b) acc[b] = bb;
        for (int i = 0; i < C_; ++i){
            float w = w1[i*C_ + t];
            #pragma unroll
            for (int b = 0; b < 16; ++b) acc[b] = fmaf(p_s[b*C_ + i], w, acc[b]);
        }
        #pragma unroll
        for (int b = 0; b < 16; ++b) hdd_s[b*C_ + t] = gelu_f(acc[b]);
    }
    __syncthreads();

    // MLP layer 2 logits
    if (t < B_*K_){
        int b = t / K_, k = t % K_;
        float acc = b2[k];
        for (int j = 0; j < C_; ++j) acc = fmaf(hdd_s[b*C_ + j], w2[j*K_ + k], acc);
        alpha_s[b*K_ + k] = acc;
    }
    __syncthreads();

    // softmax over K per sample
    if (t < B_){
        float m = -1e30f;
        #pragma unroll
        for (int k = 0; k < K_; ++k) m = fmaxf(m, alpha_s[t*K_ + k]);
        float e[K_]; float s = 0.f;
        #pragma unroll
        for (int k = 0; k < K_; ++k){ e[k] = expf(alpha_s[t*K_ + k] - m); s += e[k]; }
        float inv = 1.0f / s;
        #pragma unroll
        for (int k = 0; k < K_; ++k) alpha_s[t*K_ + k] = e[k] * inv;
    }
    __syncthreads();

    // agg_w[b][c][ij] = sum_k alpha[b][k] * kw[k][c][ij];  B*C*9 = 36864 outputs
    for (int ii = 0; ii < (B_*C_*9)/256; ++ii){
        int idx = t + ii*256;
        int b = idx / (C_*9);
        int r = idx - b*(C_*9);
        float acc = 0.f;
        #pragma unroll
        for (int k = 0; k < K_; ++k)
            acc = fmaf(alpha_s[b*K_ + k], kw[k*(C_*9) + r], acc);
        agg_out[idx] = acc;
    }
}

// --------- Kernel 3: fused dwconv + LayerNorm(C) + GELU + residual ---------
__global__ __launch_bounds__(512) void main_kernel(
    const float* __restrict__ x, const float* __restrict__ gate,
    const float* __restrict__ agg, const float* __restrict__ gamma,
    const float* __restrict__ beta, float* __restrict__ out)
{
    __shared__ __align__(8) __hip_bfloat16 conv_s[C_*W_];   // 64 KiB
    __shared__ __align__(8) __hip_bfloat16 xres_s[C_*W_];   // 64 KiB
    __shared__ float agg_s[C_*9];
    __shared__ float gate_s[C_];
    __shared__ float gam_s[C_], bet_s[C_];
    __shared__ float psum[8*W_], psumsq[8*W_];
    __shared__ float mean_s[W_], inv_s[W_];

    const int t = threadIdx.x;
    const int h = blockIdx.x;     // 0..127
    const int b = blockIdx.y;     // 0..15

    for (int i = t; i < C_*9; i += 512) agg_s[i] = agg[b*C_*9 + i];
    if (t < C_){ gate_s[t] = gate[b*C_ + t]; gam_s[t] = gamma[t]; bet_s[t] = beta[t]; }
    __syncthreads();

    const int wave = t >> 6;        // 0..7 (one wave per channel group)
    const int lane = t & 63;
    const int w2 = lane << 1;       // even pixel index this thread owns (w2, w2+1)

    float s0 = 0.f, s1 = 0.f, q0 = 0.f, q1 = 0.f;
    const float* xb = x + (size_t)b * C_ * HW_;

    for (int it = 0; it < C_/8; ++it){
        const int c = it*8 + wave;
        const float g = gate_s[c];
        const float* kc = &agg_s[c*9];
        const float* xrow = xb + (size_t)c * HW_ + (size_t)h * W_ + w2;
        float o0 = 0.f, o1 = 0.f;
        #pragma unroll
        for (int r = 0; r < 3; ++r){
            const int hh = h + r - 1;
            float2 v;
            if (hh >= 0 && hh < H_) v = *(const float2*)(xrow + (r-1)*W_);
            else { v.x = 0.f; v.y = 0.f; }
            if (r == 1){
                __hip_bfloat162 hv;
                hv.x = __float2bfloat16(v.x); hv.y = __float2bfloat16(v.y);
                *(__hip_bfloat162*)&xres_s[c*W_ + w2] = hv;   // raw x for residual
            }
            const float a = v.x * g, d = v.y * g;             // xg values
            float xm1 = __shfl_up(d, 1, 64);   if (lane == 0)  xm1 = 0.f;
            float xp2 = __shfl_down(a, 1, 64); if (lane == 63) xp2 = 0.f;
            const float k0 = kc[r*3+0], k1 = kc[r*3+1], k2 = kc[r*3+2];
            o0 = fmaf(xm1, k0, fmaf(a, k1, fmaf(d,   k2, o0)));
            o1 = fmaf(a,   k0, fmaf(d, k1, fmaf(xp2, k2, o1)));
        }
        __hip_bfloat162 cv;
        cv.x = __float2bfloat16(o0); cv.y = __float2bfloat16(o1);
        *(__hip_bfloat162*)&conv_s[c*W_ + w2] = cv;
        s0 += o0; s1 += o1;
        q0 = fmaf(o0, o0, q0); q1 = fmaf(o1, o1, q1);
    }

    psum  [wave*W_ + w2]     = s0;  psum  [wave*W_ + w2 + 1] = s1;
    psumsq[wave*W_ + w2]     = q0;  psumsq[wave*W_ + w2 + 1] = q1;
    __syncthreads();

    if (t < W_){
        float s = 0.f, q = 0.f;
        #pragma unroll
        for (int g2 = 0; g2 < 8; ++g2){ s += psum[g2*W_ + t]; q += psumsq[g2*W_ + t]; }
        float mean = s * (1.0f/(float)C_);
        float var  = q * (1.0f/(float)C_) - mean*mean;
        mean_s[t] = mean;
        inv_s[t]  = rsqrtf(var + 1e-6f);
    }
    __syncthreads();

    float* ob = out + (size_t)b * C_ * HW_ + (size_t)h * W_;
    for (int i = 0; i < (C_*W_)/1024; ++i){
        int idx = i*1024 + t*2;                 // covers C_*W_ in 32 iters
        int c = idx >> 7;
        int w = idx & (W_-1);
        __hip_bfloat162 cv = *(const __hip_bfloat162*)&conv_s[idx];
        __hip_bfloat162 xv = *(const __hip_bfloat162*)&xres_s[idx];
        float n0 = (__bfloat162float(cv.x) - mean_s[w])   * inv_s[w];
        float n1 = (__bfloat162float(cv.y) - mean_s[w+1]) * inv_s[w+1];
        float y0 = fmaf(n0, gam_s[c], bet_s[c]);
        float y1 = fmaf(n1, gam_s[c], bet_s[c]);
        float2 o;
        o.x = gelu_f(y0) + __bfloat162float(xv.x);
        o.y = gelu_f(y1) + __bfloat162float(xv.y);
        *(float2*)&ob[(size_t)c * HW_ + w] = o;
    }
}

extern "C" void kernel_launch(void* const* d_in, const int* in_sizes, int n_in,
                              void* d_out, int out_size, void* d_ws, size_t ws_size,
                              hipStream_t stream){
    const float* x    = (const float*)d_in[0];
    const float* w1   = (const float*)d_in[1];
    const float* b1   = (const float*)d_in[2];
    const float* w2   = (const float*)d_in[3];
    const float* b2   = (const float*)d_in[4];
    const float* kw   = (const float*)d_in[5];
    const float* eca  = (const float*)d_in[6];
    const float* gam  = (const float*)d_in[7];
    const float* bet  = (const float*)d_in[8];
    float* out = (float*)d_out;

    float* y    = (float*)d_ws;          // B*C
    float* gate = y + B_*C_;             // B*C
    float* agg  = gate + B_*C_;          // B*C*9

    gap_kernel<<<B_*C_, 256, 0, stream>>>(x, y);
    head_kernel<<<1, 256, 0, stream>>>(y, w1, b1, w2, b2, kw, eca, gate, agg);
    main_kernel<<<dim3(H_, B_), 512, 0, stream>>>(x, gate, agg, gam, bet, out);
}